// Round 5
// baseline (288.199 us; speedup 1.0000x reference)
//
#include <hip/hip_runtime.h>
#include <math.h>

#define NQ 6
#define SDIM 64
#define LDIM 32          // amps per lane (qubit 5 is the lane qubit)
#define NLAYERS 3
#define QBATCH 262144
#define NGATES (NLAYERS * NQ)

// ---------------------------------------------------------------------------
// The CX chain (c=q, t=q+1, q=0..4) is the LINEAR (GF(2)) index map
//   F(i) = f0(f1(f2(f3(f4(i))))),  f_c(i) = i ^ (((i>>c)&1)<<(c+1)),
// with state'[i] = state[F(i)]. Registers keep the post-encoding layout;
// during layer-l gates, abstract basis j lives at slot S_l(j) = F^(l+1)(j),
// and slot s holds abstract A_l(s) = F^-(l+1)(s). Slot bit5 = lane parity.
// Gate q pairs (j, j^e_q) -> slots differ by d = S_l(e_q) (linearity):
//   bit5(d)=0  -> lane-local pair, register offset d&31
//   bit5(d)=1  -> partner in other lane at local slot ^ (d&31)  (DPP swap)
// Facts (constexpr-derivable): F(e5)=e5, so A_l(32)=32 for all l: only q=5
// gates have lane-dependent row selection (coefficient swap), and they have
// d&31 == 0 (partner at same local slot).
// ---------------------------------------------------------------------------
struct QTabs { int S[NLAYERS][SDIM]; int A[NLAYERS][SDIM]; };
static constexpr QTabs make_tabs() {
    QTabs T{};
    int F[SDIM];
    for (int i = 0; i < SDIM; ++i) {
        int j = i;
        for (int c = NQ - 2; c >= 0; --c) j ^= ((j >> c) & 1) << (c + 1);
        F[i] = j;
    }
    int cur[SDIM];
    for (int i = 0; i < SDIM; ++i) cur[i] = i;
    for (int l = 0; l < NLAYERS; ++l) {
        for (int i = 0; i < SDIM; ++i) cur[i] = F[cur[i]];   // S_l = F^(l+1)
        for (int i = 0; i < SDIM; ++i) T.S[l][i] = cur[i];
        for (int i = 0; i < SDIM; ++i) T.A[l][cur[i]] = i;
    }
    return T;
}
static constexpr QTabs QT = make_tabs();

// xor-1 lane swap via DPP quad_perm(1,0,3,2) — full-rate VALU, no LDS.
__device__ __forceinline__ float lane_swap(float v) {
    return __int_as_float(__builtin_amdgcn_update_dpp(
        0, __float_as_int(v), 0xB1, 0xF, 0xF, true));
}

// --- Kernel 1: precompute the 18 fused gates (RZ*RY*RX) into d_ws ---
__global__ void gate_prep_kernel(const float* __restrict__ qw,
                                 float* __restrict__ gates) {
    const int g = threadIdx.x;
    if (g >= NGATES) return;
    const int p = g * 3;
    float s0 = sinf(qw[p+0] * 0.5f), c0 = cosf(qw[p+0] * 0.5f);
    float s1 = sinf(qw[p+1] * 0.5f), c1 = cosf(qw[p+1] * 0.5f);
    float s2 = sinf(qw[p+2] * 0.5f), c2 = cosf(qw[p+2] * 0.5f);
    const float m00r =  c1*c0, m00i =  s1*s0;
    const float m01r = -s1*c0, m01i = -c1*s0;
    const float m10r =  s1*c0, m10i = -c1*s0;
    const float m11r =  c1*c0, m11i = -s1*s0;
    float* o = gates + g*8;
    o[0] = c2*m00r + s2*m00i;  o[1] = c2*m00i - s2*m00r;
    o[2] = c2*m01r + s2*m01i;  o[3] = c2*m01i - s2*m01r;
    o[4] = c2*m10r - s2*m10i;  o[5] = c2*m10i + s2*m10r;
    o[6] = c2*m11r - s2*m11i;  o[7] = c2*m11i + s2*m11r;
}

// --- Kernel 2: TWO lanes per sample; 32 complex amps per lane in VGPRs. ---
__global__ __launch_bounds__(256) void qnn_fused_kernel(
    const float* __restrict__ x,
    const float* __restrict__ pre_w1, const float* __restrict__ pre_b1,
    const float* __restrict__ pre_w2, const float* __restrict__ pre_b2,
    const float* __restrict__ gates,
    const float* __restrict__ post_w1, const float* __restrict__ post_b1,
    const float* __restrict__ post_w2, const float* __restrict__ post_b2,
    float* __restrict__ out)
{
    const int tid  = blockIdx.x * blockDim.x + threadIdx.x;
    const int samp = tid >> 1;
    const int p    = tid & 1;            // value of qubit 5 held by this lane

    const float4 xv = reinterpret_cast<const float4*>(x)[samp];

    // --- pre-net (redundant across the lane pair; tiny) ---
    float h[16];
    #pragma unroll
    for (int j = 0; j < 16; ++j) {
        float a = pre_b1[j];
        a = fmaf(xv.x, pre_w1[0*16+j], a);
        a = fmaf(xv.y, pre_w1[1*16+j], a);
        a = fmaf(xv.z, pre_w1[2*16+j], a);
        a = fmaf(xv.w, pre_w1[3*16+j], a);
        h[j] = fmaxf(a, 0.f);
    }

    // --- angles (all 6), then encoding product state over local qubits 0..4,
    // scaled by this lane's qubit-5 factor ---
    float ang[NQ];
    #pragma unroll
    for (int q = 0; q < NQ; ++q) {
        float a = pre_b2[q];
        #pragma unroll
        for (int j = 0; j < 16; ++j) a = fmaf(h[j], pre_w2[j*NQ+q], a);
        ang[q] = tanhf(a) * 0.5f;
    }
    float re[LDIM], im[LDIM];
    {
        const float c5 = __cosf(ang[5]), s5 = __sinf(ang[5]);
        const float f0 = (c5 - s5) * 0.70710678118654752440f;
        const float f1 = (c5 + s5) * 0.70710678118654752440f;
        re[0] = p ? f1 : f0;
    }
    #pragma unroll
    for (int q = 0; q < 5; ++q) {
        const float c = __cosf(ang[q]), s = __sinf(ang[q]);
        const float v0 = (c - s) * 0.70710678118654752440f;
        const float v1 = (c + s) * 0.70710678118654752440f;
        #pragma unroll
        for (int i = 0; i < (1 << q); ++i) {
            re[i | (1 << q)] = re[i] * v1;
            re[i] = re[i] * v0;
        }
    }
    // im[] is initialized by gate 0 (state is purely real until then).

    // --- 18 fused variational gates ---
    #pragma unroll
    for (int g = 0; g < NGATES; ++g) {
        const int  l     = g / NQ, q = g % NQ;
        const int  dq    = QT.S[l][1 << q];
        const int  d31   = dq & (LDIM - 1);
        const bool cross = ((dq >> 5) & 1) != 0;
        const bool k5    = (q == 5);     // == bit_q(A_l(32)), A_l(32)=32

        const float* gp = gates + g * 8;   // uniform -> s_load
        const float g00r = gp[0], g00i = gp[1], g01r = gp[2], g01i = gp[3];
        const float g10r = gp[4], g10i = gp[5], g11r = gp[6], g11i = gp[7];
        // row/col swap for odd lane on q=5 gates: G'[x][y] = G[1-x][1-y]
        float h00r = g00r, h00i = g00i, h01r = g01r, h01i = g01i;
        float h10r = g10r, h10i = g10i, h11r = g11r, h11i = g11i;
        if (k5) {
            const bool sw = (p != 0);
            h00r = sw ? g11r : g00r;  h00i = sw ? g11i : g00i;
            h01r = sw ? g10r : g01r;  h01i = sw ? g10i : g01i;
            h10r = sw ? g01r : g10r;  h10i = sw ? g01i : g10i;
            h11r = sw ? g00r : g11r;  h11i = sw ? g00i : g11i;
        }

        if (!cross) {
            // lane-local: 16 pairs (sa: row0, sb=sa^d31: row1), all compile-time
            #pragma unroll
            for (int sa = 0; sa < LDIM; ++sa) {
                if ((QT.A[l][sa] >> q) & 1) continue;   // visit row-0 slots only
                const int sb = sa ^ d31;
                if (g == 0) {   // state purely real: half the FMAs, inits im[]
                    const float r0 = re[sa], r1 = re[sb];
                    re[sa] = h00r*r0 + h01r*r1;
                    im[sa] = h00i*r0 + h01i*r1;
                    re[sb] = h10r*r0 + h11r*r1;
                    im[sb] = h10i*r0 + h11i*r1;
                } else {
                    const float r0 = re[sa], u0 = im[sa];
                    const float r1 = re[sb], u1 = im[sb];
                    re[sa] = h00r*r0 - h00i*u0 + h01r*r1 - h01i*u1;
                    im[sa] = h00r*u0 + h00i*r0 + h01r*u1 + h01i*r1;
                    re[sb] = h10r*r0 - h10i*u0 + h11r*r1 - h11i*u1;
                    im[sb] = h10r*u0 + h10i*r0 + h11r*u1 + h11i*r1;
                }
            }
        } else if (d31 == 0) {
            // q=5 gates: partner is SAME local slot in the other lane
            #pragma unroll
            for (int s = 0; s < LDIM; ++s) {
                const int rb = (QT.A[l][s] >> q) & 1;   // compile-time
                const float pr = lane_swap(re[s]), pi = lane_swap(im[s]);
                const float r0 = re[s], u0 = im[s];
                const float crr = rb ? h11r : h00r, cri = rb ? h11i : h00i;
                const float cpr = rb ? h10r : h01r, cpi = rb ? h10i : h01i;
                re[s] = crr*r0 - cri*u0 + cpr*pr - cpi*pi;
                im[s] = crr*u0 + cri*r0 + cpr*pi + cpi*pr;
            }
        } else {
            // cross-lane with register offset: process disjoint pair-blocks;
            // all 4 DPP fetches precede the writes -> old values guaranteed.
            #pragma unroll
            for (int sa = 0; sa < LDIM; ++sa) {
                const int sb = sa ^ d31;
                if (sb < sa) continue;
                const int rbA = (QT.A[l][sa] >> q) & 1;   // compile-time
                const int rbB = rbA ^ 1;
                const float prA = lane_swap(re[sb]), piA = lane_swap(im[sb]);
                const float prB = lane_swap(re[sa]), piB = lane_swap(im[sa]);
                {
                    const float r0 = re[sa], u0 = im[sa];
                    const float crr = rbA ? h11r : h00r, cri = rbA ? h11i : h00i;
                    const float cpr = rbA ? h10r : h01r, cpi = rbA ? h10i : h01i;
                    re[sa] = crr*r0 - cri*u0 + cpr*prA - cpi*piA;
                    im[sa] = crr*u0 + cri*r0 + cpr*piA + cpi*prA;
                }
                {
                    const float r0 = re[sb], u0 = im[sb];
                    const float crr = rbB ? h11r : h00r, cri = rbB ? h11i : h00i;
                    const float cpr = rbB ? h10r : h01r, cpi = rbB ? h10i : h01i;
                    re[sb] = crr*r0 - cri*u0 + cpr*prB - cpi*piB;
                    im[sb] = crr*u0 + cri*r0 + cpr*piB + cpi*prB;
                }
            }
        }
    }

    // --- probabilities (in place) ---
    #pragma unroll
    for (int s = 0; s < LDIM; ++s) re[s] = fmaf(re[s], re[s], im[s]*im[s]);

    // --- per-qubit Z expectations; cross-lane reduce via DPP ---
    float ex[NQ];
    #pragma unroll
    for (int q = 0; q < NQ; ++q) {
        float acc = 0.f;
        #pragma unroll
        for (int s = 0; s < LDIM; ++s) {
            const int sgn = (QT.A[NLAYERS-1][s] >> q) & 1;   // compile-time
            acc = sgn ? (acc - re[s]) : (acc + re[s]);
        }
        if (q == 5) acc = p ? -acc : acc;   // abstract bit5 == lane parity
        acc += lane_swap(acc);
        ex[q] = acc;
    }

    // --- post-net (redundant across lane pair; all weights uniform s_loads) ---
    float h2[16];
    #pragma unroll
    for (int j = 0; j < 16; ++j) {
        float a = post_b1[j];
        #pragma unroll
        for (int q = 0; q < NQ; ++q) a = fmaf(ex[q], post_w1[q*16+j], a);
        h2[j] = fmaxf(a, 0.f);
    }
    float o0 = post_b2[0], o1 = post_b2[1], o2 = post_b2[2], o3 = post_b2[3];
    #pragma unroll
    for (int j = 0; j < 16; ++j) {
        o0 = fmaf(h2[j], post_w2[j*4+0], o0);
        o1 = fmaf(h2[j], post_w2[j*4+1], o1);
        o2 = fmaf(h2[j], post_w2[j*4+2], o2);
        o3 = fmaf(h2[j], post_w2[j*4+3], o3);
    }
    if (p == 0)
        reinterpret_cast<float4*>(out)[samp] = make_float4(o0, o1, o2, o3);
}

extern "C" void kernel_launch(void* const* d_in, const int* in_sizes, int n_in,
                              void* d_out, int out_size, void* d_ws, size_t ws_size,
                              hipStream_t stream) {
    const float* x       = (const float*)d_in[0];
    const float* pre_w1  = (const float*)d_in[1];
    const float* pre_b1  = (const float*)d_in[2];
    const float* pre_w2  = (const float*)d_in[3];
    const float* pre_b2  = (const float*)d_in[4];
    const float* qw      = (const float*)d_in[5];
    const float* post_w1 = (const float*)d_in[6];
    const float* post_b1 = (const float*)d_in[7];
    const float* post_w2 = (const float*)d_in[8];
    const float* post_b2 = (const float*)d_in[9];
    float* out   = (float*)d_out;
    float* gates = (float*)d_ws;   // 18*8 floats = 576 B

    gate_prep_kernel<<<1, 64, 0, stream>>>(qw, gates);

    const int block = 256;
    const int grid  = (2 * QBATCH) / block;   // 2 lanes/sample -> 2048 blocks
    qnn_fused_kernel<<<grid, block, 0, stream>>>(
        x, pre_w1, pre_b1, pre_w2, pre_b2, gates,
        post_w1, post_b1, post_w2, post_b2, out);
}

// Round 6
// 89.431 us; speedup vs baseline: 3.2226x; 3.2226x over previous
//
#include <hip/hip_runtime.h>
#include <math.h>

#define NQ 6
#define SDIM 64
#define LDIM 32          // amps per lane (qubit 5 is the lane-parity qubit)
#define NLAYERS 3
#define QBATCH 262144
#define NGATES (NLAYERS * NQ)

// xor-1 lane swap via DPP quad_perm(1,0,3,2) — full-rate VALU, no LDS.
__device__ __forceinline__ float lane_swap(float v) {
    return __int_as_float(__builtin_amdgcn_update_dpp(
        0, __float_as_int(v), 0xB1, 0xF, 0xF, true));
}
__device__ __forceinline__ void fswap(float& a, float& b) {
    float t = a; a = b; b = t;
}
__device__ __forceinline__ float tanh_fast(float a) {
    // tanh(a) = 1 - 2/(e^{2a}+1); v_exp-based, ~5 instrs, ~1e-6 abs err
    const float e = __expf(2.f * a);
    return 1.f - 2.f * __builtin_amdgcn_rcpf(e + 1.f);
}

// --- Kernel 1: precompute the 18 fused gates (RZ*RY*RX) into d_ws ---
__global__ void gate_prep_kernel(const float* __restrict__ qw,
                                 float* __restrict__ gates) {
    const int g = threadIdx.x;
    if (g >= NGATES) return;
    const int p = g * 3;
    float s0 = sinf(qw[p+0] * 0.5f), c0 = cosf(qw[p+0] * 0.5f);
    float s1 = sinf(qw[p+1] * 0.5f), c1 = cosf(qw[p+1] * 0.5f);
    float s2 = sinf(qw[p+2] * 0.5f), c2 = cosf(qw[p+2] * 0.5f);
    const float m00r =  c1*c0, m00i =  s1*s0;
    const float m01r = -s1*c0, m01i = -c1*s0;
    const float m10r =  s1*c0, m10i = -c1*s0;
    const float m11r =  c1*c0, m11i = -s1*s0;
    float* o = gates + g*8;
    o[0] = c2*m00r + s2*m00i;  o[1] = c2*m00i - s2*m00r;
    o[2] = c2*m01r + s2*m01i;  o[3] = c2*m01i - s2*m01r;
    o[4] = c2*m10r - s2*m10i;  o[5] = c2*m10i + s2*m10r;
    o[6] = c2*m11r - s2*m11i;  o[7] = c2*m11i + s2*m11r;
}

// --- Kernel 2: two lanes per sample; 32 complex amps/lane in VGPRs.
// Canonical basis order throughout: CX gates are applied PHYSICALLY
// (register swaps + DPP), which makes every layer's code identical ->
// the layer loop stays ROLLED and total code fits the 32 KB I$.
// (Rounds 1-5: ~50 KB unrolled code -> ~90K cyc/wave fixed cost.) ---
__global__ __launch_bounds__(256) void qnn_fused_kernel(
    const float* __restrict__ x,
    const float* __restrict__ pre_w1, const float* __restrict__ pre_b1,
    const float* __restrict__ pre_w2, const float* __restrict__ pre_b2,
    const float* __restrict__ gates,
    const float* __restrict__ post_w1, const float* __restrict__ post_b1,
    const float* __restrict__ post_w2, const float* __restrict__ post_b2,
    float* __restrict__ out)
{
    const int tid  = blockIdx.x * blockDim.x + threadIdx.x;
    const int samp = tid >> 1;
    const int p    = tid & 1;            // this lane's value of qubit 5

    const float4 xv = reinterpret_cast<const float4*>(x)[samp];

    // --- pre-net ---
    float h[16];
    #pragma unroll
    for (int j = 0; j < 16; ++j) {
        float a = pre_b1[j];
        a = fmaf(xv.x, pre_w1[0*16+j], a);
        a = fmaf(xv.y, pre_w1[1*16+j], a);
        a = fmaf(xv.z, pre_w1[2*16+j], a);
        a = fmaf(xv.w, pre_w1[3*16+j], a);
        h[j] = fmaxf(a, 0.f);
    }

    // --- angles ---
    float ang[NQ];
    #pragma unroll
    for (int q = 0; q < NQ; ++q) {
        float a = pre_b2[q];
        #pragma unroll
        for (int j = 0; j < 16; ++j) a = fmaf(h[j], pre_w2[j*NQ+q], a);
        ang[q] = tanh_fast(a) * 0.5f;
    }

    // --- encoding: real product state over local qubits 0..4, scaled by
    // this lane's qubit-5 factor ---
    float re[LDIM], im[LDIM];
    {
        const float c5 = __cosf(ang[5]), s5 = __sinf(ang[5]);
        const float f0 = (c5 - s5) * 0.70710678118654752440f;
        const float f1 = (c5 + s5) * 0.70710678118654752440f;
        re[0] = p ? f1 : f0;
    }
    #pragma unroll
    for (int q = 0; q < 5; ++q) {
        const float c = __cosf(ang[q]), s = __sinf(ang[q]);
        const float v0 = (c - s) * 0.70710678118654752440f;
        const float v1 = (c + s) * 0.70710678118654752440f;
        #pragma unroll
        for (int i = 0; i < (1 << q); ++i) {
            re[i | (1 << q)] = re[i] * v1;
            re[i] = re[i] * v0;
        }
    }
    #pragma unroll
    for (int s = 0; s < LDIM; ++s) im[s] = 0.f;

    // --- variational layers: ROLLED (code appears once) ---
    #pragma unroll 1
    for (int l = 0; l < NLAYERS; ++l) {
        // CX(c, c+1), c = 0..3: local register swaps (canonical order kept)
        #pragma unroll
        for (int c = 0; c < 4; ++c) {
            #pragma unroll
            for (int s = 0; s < LDIM; ++s) {
                if (((s >> c) & 1) && !((s >> (c + 1)) & 1)) {
                    const int t = s ^ (1 << (c + 1));
                    fswap(re[s], re[t]);
                    fswap(im[s], im[t]);
                }
            }
        }
        // CX(4, 5): slots with bit4=1 exchange with the other lane
        #pragma unroll
        for (int s = 16; s < LDIM; ++s) {
            re[s] = lane_swap(re[s]);
            im[s] = lane_swap(im[s]);
        }

        const float* lg = gates + l * (NQ * 8);   // uniform -> s_load

        // gates q = 0..4: lane-local pairs (sa, sa^2^q)
        #pragma unroll
        for (int q = 0; q < 5; ++q) {
            const float* gp = lg + q * 8;
            const float g00r = gp[0], g00i = gp[1], g01r = gp[2], g01i = gp[3];
            const float g10r = gp[4], g10i = gp[5], g11r = gp[6], g11i = gp[7];
            #pragma unroll
            for (int k = 0; k < 16; ++k) {
                const int sa = ((k >> q) << (q + 1)) | (k & ((1 << q) - 1));
                const int sb = sa | (1 << q);
                const float r0 = re[sa], u0 = im[sa];
                const float r1 = re[sb], u1 = im[sb];
                re[sa] = g00r*r0 - g00i*u0 + g01r*r1 - g01i*u1;
                im[sa] = g00r*u0 + g00i*r0 + g01r*u1 + g01i*r1;
                re[sb] = g10r*r0 - g10i*u0 + g11r*r1 - g11i*u1;
                im[sb] = g10r*u0 + g10i*r0 + g11r*u1 + g11i*r1;
            }
        }
        // gate q = 5: partner is the SAME slot in the other lane; this lane's
        // row index is its parity p
        {
            const float* gp = lg + 5 * 8;
            const float g00r = gp[0], g00i = gp[1], g01r = gp[2], g01i = gp[3];
            const float g10r = gp[4], g10i = gp[5], g11r = gp[6], g11i = gp[7];
            const float crr = p ? g11r : g00r, cri = p ? g11i : g00i;
            const float cpr = p ? g10r : g01r, cpi = p ? g10i : g01i;
            #pragma unroll
            for (int s = 0; s < LDIM; ++s) {
                const float pr = lane_swap(re[s]), pi = lane_swap(im[s]);
                const float r0 = re[s], u0 = im[s];
                re[s] = crr*r0 - cri*u0 + cpr*pr - cpi*pi;
                im[s] = crr*u0 + cri*r0 + cpr*pi + cpi*pr;
            }
        }
    }

    // --- probabilities (in place) ---
    #pragma unroll
    for (int s = 0; s < LDIM; ++s) re[s] = fmaf(re[s], re[s], im[s]*im[s]);

    // --- per-qubit Z expectations (canonical signs); cross-lane DPP reduce ---
    float ex[NQ];
    #pragma unroll
    for (int q = 0; q < NQ; ++q) {
        float acc = 0.f;
        #pragma unroll
        for (int s = 0; s < LDIM; ++s) {
            const int sgn = (q < 5) ? ((s >> q) & 1) : 0;
            acc = sgn ? (acc - re[s]) : (acc + re[s]);
        }
        if (q == 5) acc = p ? -acc : acc;
        acc += lane_swap(acc);
        ex[q] = acc;
    }

    // --- post-net ---
    float h2[16];
    #pragma unroll
    for (int j = 0; j < 16; ++j) {
        float a = post_b1[j];
        #pragma unroll
        for (int q = 0; q < NQ; ++q) a = fmaf(ex[q], post_w1[q*16+j], a);
        h2[j] = fmaxf(a, 0.f);
    }
    float o0 = post_b2[0], o1 = post_b2[1], o2 = post_b2[2], o3 = post_b2[3];
    #pragma unroll
    for (int j = 0; j < 16; ++j) {
        o0 = fmaf(h2[j], post_w2[j*4+0], o0);
        o1 = fmaf(h2[j], post_w2[j*4+1], o1);
        o2 = fmaf(h2[j], post_w2[j*4+2], o2);
        o3 = fmaf(h2[j], post_w2[j*4+3], o3);
    }
    if (p == 0)
        reinterpret_cast<float4*>(out)[samp] = make_float4(o0, o1, o2, o3);
}

extern "C" void kernel_launch(void* const* d_in, const int* in_sizes, int n_in,
                              void* d_out, int out_size, void* d_ws, size_t ws_size,
                              hipStream_t stream) {
    const float* x       = (const float*)d_in[0];
    const float* pre_w1  = (const float*)d_in[1];
    const float* pre_b1  = (const float*)d_in[2];
    const float* pre_w2  = (const float*)d_in[3];
    const float* pre_b2  = (const float*)d_in[4];
    const float* qw      = (const float*)d_in[5];
    const float* post_w1 = (const float*)d_in[6];
    const float* post_b1 = (const float*)d_in[7];
    const float* post_w2 = (const float*)d_in[8];
    const float* post_b2 = (const float*)d_in[9];
    float* out   = (float*)d_out;
    float* gates = (float*)d_ws;   // 18*8 floats = 576 B

    gate_prep_kernel<<<1, 64, 0, stream>>>(qw, gates);

    const int block = 256;
    const int grid  = (2 * QBATCH) / block;   // 2 lanes/sample -> 2048 blocks
    qnn_fused_kernel<<<grid, block, 0, stream>>>(
        x, pre_w1, pre_b1, pre_w2, pre_b2, gates,
        post_w1, post_b1, post_w2, post_b2, out);
}

// Round 7
// 57.719 us; speedup vs baseline: 4.9932x; 1.5494x over previous
//
#include <hip/hip_runtime.h>
#include <math.h>

#define NQ 6
#define SDIM 64
#define LDIM 32          // amps per lane (qubit 5 = lane-parity qubit)
#define NLAYERS 3
#define QBATCH 262144
#define NGATES (NLAYERS * NQ)
#define GSTRIDE 40       // floats per gate record in d_ws

typedef float f2 __attribute__((ext_vector_type(2)));

// packed fp32 fma: <2 x float> fma -> v_pk_fma_f32 on gfx950
__device__ __forceinline__ f2 pk_fma(f2 a, f2 b, f2 c) {
    return __builtin_elementwise_fma(a, b, c);
}
#define BCX(v) __builtin_shufflevector((v), (v), 0, 0)   // (v.x, v.x) -> op_sel
#define BCY(v) __builtin_shufflevector((v), (v), 1, 1)   // (v.y, v.y)

// xor-1 lane swap via DPP quad_perm(1,0,3,2) — full-rate VALU, no LDS.
__device__ __forceinline__ float lane_swap(float v) {
    return __int_as_float(__builtin_amdgcn_update_dpp(
        0, __float_as_int(v), 0xB1, 0xF, 0xF, true));
}
__device__ __forceinline__ f2 lane_swap2(f2 v) {
    f2 r; r.x = lane_swap(v.x); r.y = lane_swap(v.y); return r;
}
__device__ __forceinline__ float tanh_fast(float a) {
    const float e = __expf(2.f * a);
    return 1.f - 2.f * __builtin_amdgcn_rcpf(e + 1.f);
}

// --- Kernel 1: fused gates (RZ*RY*RX) pre-swizzled for packed consumption.
// Per gate (40 floats): 12 splat pairs [a00r a00i n00i a01r a01i n01i a10r
// a10i n10i a11r a11i n11i] (each duplicated; n = negated imag), then 6
// mixed-row pairs [A=(c00r,c10r) Ai=(c00i,c10i) nAi C=(c01r,c11r) Ci nCi]
// used by the in-register (q=0) gate. All become 64-bit SGPR operands. ---
__global__ void gate_prep_kernel(const float* __restrict__ qw,
                                 float* __restrict__ gates) {
    const int g = threadIdx.x;
    if (g >= NGATES) return;
    const int p = g * 3;
    float s0 = sinf(qw[p+0] * 0.5f), c0 = cosf(qw[p+0] * 0.5f);
    float s1 = sinf(qw[p+1] * 0.5f), c1 = cosf(qw[p+1] * 0.5f);
    float s2 = sinf(qw[p+2] * 0.5f), c2 = cosf(qw[p+2] * 0.5f);
    const float m00r =  c1*c0, m00i =  s1*s0;
    const float m01r = -s1*c0, m01i = -c1*s0;
    const float m10r =  s1*c0, m10i = -c1*s0;
    const float m11r =  c1*c0, m11i = -s1*s0;
    const float g00r = c2*m00r + s2*m00i, g00i = c2*m00i - s2*m00r;
    const float g01r = c2*m01r + s2*m01i, g01i = c2*m01i - s2*m01r;
    const float g10r = c2*m10r - s2*m10i, g10i = c2*m10i + s2*m10r;
    const float g11r = c2*m11r - s2*m11i, g11i = c2*m11i + s2*m11r;
    float* o = gates + g * GSTRIDE;
    o[0]=o[1]=g00r;  o[2]=o[3]=g00i;  o[4]=o[5]=-g00i;
    o[6]=o[7]=g01r;  o[8]=o[9]=g01i;  o[10]=o[11]=-g01i;
    o[12]=o[13]=g10r; o[14]=o[15]=g10i; o[16]=o[17]=-g10i;
    o[18]=o[19]=g11r; o[20]=o[21]=g11i; o[22]=o[23]=-g11i;
    o[24]=g00r; o[25]=g10r;   // A
    o[26]=g00i; o[27]=g10i;   // Ai
    o[28]=-g00i; o[29]=-g10i; // nAi
    o[30]=g01r; o[31]=g11r;   // C
    o[32]=g01i; o[33]=g11i;   // Ci
    o[34]=-g01i; o[35]=-g11i; // nCi
    o[36]=o[37]=o[38]=o[39]=0.f;
}

// --- Kernel 2: two lanes per sample; state as f2 R[16],U[16] packed along
// slot bit0 (slot s -> R[s>>1][s&1]). Gates q=1..4 pack perfectly (same
// coefficient row for both packed slots, splat SGPR operands, zero shuffles);
// q=0 uses op_sel broadcasts; q=5 is cross-lane DPP. Layer loop ROLLED
// (round 6: code must fit 32 KB I$). ---
#define RE(s) (R[(s) >> 1][(s) & 1])
__global__ __launch_bounds__(256) void qnn_fused_kernel(
    const float* __restrict__ x,
    const float* __restrict__ pre_w1, const float* __restrict__ pre_b1,
    const float* __restrict__ pre_w2, const float* __restrict__ pre_b2,
    const float* __restrict__ gates,
    const float* __restrict__ post_w1, const float* __restrict__ post_b1,
    const float* __restrict__ post_w2, const float* __restrict__ post_b2,
    float* __restrict__ out)
{
    const int tid  = blockIdx.x * blockDim.x + threadIdx.x;
    const int samp = tid >> 1;
    const int p    = tid & 1;            // this lane's value of qubit 5

    const float4 xv = reinterpret_cast<const float4*>(x)[samp];

    // --- pre-net ---
    float h[16];
    #pragma unroll
    for (int j = 0; j < 16; ++j) {
        float a = pre_b1[j];
        a = fmaf(xv.x, pre_w1[0*16+j], a);
        a = fmaf(xv.y, pre_w1[1*16+j], a);
        a = fmaf(xv.z, pre_w1[2*16+j], a);
        a = fmaf(xv.w, pre_w1[3*16+j], a);
        h[j] = fmaxf(a, 0.f);
    }

    // --- angles ---
    float ang[NQ];
    #pragma unroll
    for (int q = 0; q < NQ; ++q) {
        float a = pre_b2[q];
        #pragma unroll
        for (int j = 0; j < 16; ++j) a = fmaf(h[j], pre_w2[j*NQ+q], a);
        ang[q] = tanh_fast(a) * 0.5f;
    }

    // --- encoding: RY(a)·H|0> product state over local qubits 0..4, scaled
    // by this lane's qubit-5 factor (state purely real) ---
    f2 R[16], U[16];
    {
        const float c5 = __cosf(ang[5]), s5 = __sinf(ang[5]);
        const float f0 = (c5 - s5) * 0.70710678118654752440f;
        const float f1 = (c5 + s5) * 0.70710678118654752440f;
        RE(0) = p ? f1 : f0;
    }
    #pragma unroll
    for (int q = 0; q < 5; ++q) {
        const float c = __cosf(ang[q]), s = __sinf(ang[q]);
        const float v0 = (c - s) * 0.70710678118654752440f;
        const float v1 = (c + s) * 0.70710678118654752440f;
        #pragma unroll
        for (int i = 0; i < (1 << q); ++i) {
            RE(i | (1 << q)) = RE(i) * v1;
            RE(i) = RE(i) * v0;
        }
    }
    const f2 zero2 = {0.f, 0.f};
    #pragma unroll
    for (int j = 0; j < 16; ++j) U[j] = zero2;

    const f2* gpack = reinterpret_cast<const f2*>(gates);

    // --- variational layers: ROLLED ---
    #pragma unroll 1
    for (int l = 0; l < NLAYERS; ++l) {
        // CX(0,1): swap odd slots across adjacent packed regs (.y comps)
        #pragma unroll
        for (int j = 0; j < 16; j += 2) {
            float t;
            t = R[j].y; R[j].y = R[j+1].y; R[j+1].y = t;
            t = U[j].y; U[j].y = U[j+1].y; U[j+1].y = t;
        }
        // CX(c,c+1), c=1..3: whole packed-reg swaps (j bit c-1 set, bit c clear)
        #pragma unroll
        for (int c = 1; c < 4; ++c) {
            #pragma unroll
            for (int j = 0; j < 16; ++j) {
                if (((j >> (c-1)) & 1) && !((j >> c) & 1)) {
                    const int t = j | (1 << c);
                    f2 tmp;
                    tmp = R[j]; R[j] = R[t]; R[t] = tmp;
                    tmp = U[j]; U[j] = U[t]; U[t] = tmp;
                }
            }
        }
        // CX(4,5): slots with bit4=1 (j >= 8) exchange with the other lane
        #pragma unroll
        for (int j = 8; j < 16; ++j) {
            R[j] = lane_swap2(R[j]);
            U[j] = lane_swap2(U[j]);
        }

        const f2* lg = gpack + l * (NQ * (GSTRIDE / 2));

        // --- gate q=0: pairs inside each packed reg (mixed-row coefficients,
        // op_sel broadcasts) ---
        {
            const f2* gb = lg;
            const f2 A = gb[12], Ai = gb[13], nAi = gb[14];
            const f2 C = gb[15], Ci = gb[16], nCi = gb[17];
            #pragma unroll
            for (int j = 0; j < 16; ++j) {
                const f2 z = R[j], u = U[j];
                const f2 br0 = BCX(z), br1 = BCY(z);
                const f2 bu0 = BCX(u), bu1 = BCY(u);
                R[j] = pk_fma(nCi, bu1, pk_fma(C,  br1, pk_fma(nAi, bu0, A  * br0)));
                U[j] = pk_fma(C,   bu1, pk_fma(Ci, br1, pk_fma(A,   bu0, Ai * br0)));
            }
        }
        // --- gates q=1..4: packed-pair regs, splat coefficients, no shuffles ---
        #pragma unroll
        for (int q = 1; q < 5; ++q) {
            const f2* gb = lg + q * (GSTRIDE / 2);
            const f2 a00r = gb[0], a00i = gb[1],  n00i = gb[2];
            const f2 a01r = gb[3], a01i = gb[4],  n01i = gb[5];
            const f2 a10r = gb[6], a10i = gb[7],  n10i = gb[8];
            const f2 a11r = gb[9], a11i = gb[10], n11i = gb[11];
            const int bit = 1 << (q - 1);
            #pragma unroll
            for (int m = 0; m < 8; ++m) {
                const int ja = ((m >> (q-1)) << q) | (m & (bit - 1));
                const int jb = ja | bit;
                const f2 zr0 = R[ja], zu0 = U[ja];
                const f2 zr1 = R[jb], zu1 = U[jb];
                R[ja] = pk_fma(n01i, zu1, pk_fma(a01r, zr1, pk_fma(n00i, zu0, a00r * zr0)));
                U[ja] = pk_fma(a01r, zu1, pk_fma(a01i, zr1, pk_fma(a00r, zu0, a00i * zr0)));
                R[jb] = pk_fma(n11i, zu1, pk_fma(a11r, zr1, pk_fma(n10i, zu0, a10r * zr0)));
                U[jb] = pk_fma(a11r, zu1, pk_fma(a11i, zr1, pk_fma(a10r, zu0, a10i * zr0)));
            }
        }
        // --- gate q=5: partner = same slot, other lane; row by lane parity ---
        {
            const f2* gb = lg + 5 * (GSTRIDE / 2);
            const bool sw = (p != 0);
            const f2 rrr  = sw ? gb[9]  : gb[0];
            const f2 rri  = sw ? gb[10] : gb[1];
            const f2 nrri = sw ? gb[11] : gb[2];
            const f2 rpr  = sw ? gb[6]  : gb[3];
            const f2 rpi  = sw ? gb[7]  : gb[4];
            const f2 nrpi = sw ? gb[8]  : gb[5];
            #pragma unroll
            for (int j = 0; j < 16; ++j) {
                const f2 z = R[j], u = U[j];
                const f2 pr = lane_swap2(z), pu = lane_swap2(u);
                R[j] = pk_fma(nrpi, pu, pk_fma(rpr, pr, pk_fma(nrri, u, rrr * z)));
                U[j] = pk_fma(rpr,  pu, pk_fma(rpi, pr, pk_fma(rrr,  u, rri * z)));
            }
        }
    }

    // --- probabilities (packed) ---
    f2 P[16];
    #pragma unroll
    for (int j = 0; j < 16; ++j) P[j] = pk_fma(U[j], U[j], R[j] * R[j]);

    // --- per-qubit Z expectations ---
    f2 T = P[0];
    #pragma unroll
    for (int j = 1; j < 16; ++j) T = T + P[j];
    float sj[16];
    #pragma unroll
    for (int j = 0; j < 16; ++j) sj[j] = P[j].x + P[j].y;

    float ex[NQ];
    ex[0] = T.x - T.y;                       // sign = slot bit0
    #pragma unroll
    for (int q = 1; q < 5; ++q) {
        float acc = 0.f;
        #pragma unroll
        for (int j = 0; j < 16; ++j)
            acc = ((j >> (q-1)) & 1) ? (acc - sj[j]) : (acc + sj[j]);
        ex[q] = acc;
    }
    {
        const float tot = T.x + T.y;
        ex[5] = p ? -tot : tot;              // abstract bit5 = lane parity
    }
    #pragma unroll
    for (int q = 0; q < NQ; ++q) ex[q] += lane_swap(ex[q]);

    // --- post-net ---
    float h2[16];
    #pragma unroll
    for (int j = 0; j < 16; ++j) {
        float a = post_b1[j];
        #pragma unroll
        for (int q = 0; q < NQ; ++q) a = fmaf(ex[q], post_w1[q*16+j], a);
        h2[j] = fmaxf(a, 0.f);
    }
    float o0 = post_b2[0], o1 = post_b2[1], o2 = post_b2[2], o3 = post_b2[3];
    #pragma unroll
    for (int j = 0; j < 16; ++j) {
        o0 = fmaf(h2[j], post_w2[j*4+0], o0);
        o1 = fmaf(h2[j], post_w2[j*4+1], o1);
        o2 = fmaf(h2[j], post_w2[j*4+2], o2);
        o3 = fmaf(h2[j], post_w2[j*4+3], o3);
    }
    if (p == 0)
        reinterpret_cast<float4*>(out)[samp] = make_float4(o0, o1, o2, o3);
}

extern "C" void kernel_launch(void* const* d_in, const int* in_sizes, int n_in,
                              void* d_out, int out_size, void* d_ws, size_t ws_size,
                              hipStream_t stream) {
    const float* x       = (const float*)d_in[0];
    const float* pre_w1  = (const float*)d_in[1];
    const float* pre_b1  = (const float*)d_in[2];
    const float* pre_w2  = (const float*)d_in[3];
    const float* pre_b2  = (const float*)d_in[4];
    const float* qw      = (const float*)d_in[5];
    const float* post_w1 = (const float*)d_in[6];
    const float* post_b1 = (const float*)d_in[7];
    const float* post_w2 = (const float*)d_in[8];
    const float* post_b2 = (const float*)d_in[9];
    float* out   = (float*)d_out;
    float* gates = (float*)d_ws;   // 18*40 floats = 2880 B

    gate_prep_kernel<<<1, 64, 0, stream>>>(qw, gates);

    const int block = 256;
    const int grid  = (2 * QBATCH) / block;   // 2 lanes/sample -> 2048 blocks
    qnn_fused_kernel<<<grid, block, 0, stream>>>(
        x, pre_w1, pre_b1, pre_w2, pre_b2, gates,
        post_w1, post_b1, post_w2, post_b2, out);
}

// Round 9
// 26.145 us; speedup vs baseline: 11.0231x; 2.2076x over previous
//
#include <hip/hip_runtime.h>
#include <math.h>

#define NQ 6
#define NLAYERS 3
#define QBATCH 262144
#define NGATES 18
#define GSTRIDE 40

typedef float  f2  __attribute__((ext_vector_type(2)));
typedef float  f4v __attribute__((ext_vector_type(4)));
typedef __fp16 h2v __attribute__((ext_vector_type(2)));
typedef __fp16 h8v __attribute__((ext_vector_type(8)));

__device__ __forceinline__ float lane_swap(float v) {
    return __int_as_float(__builtin_amdgcn_update_dpp(
        0, __float_as_int(v), 0xB1, 0xF, 0xF, true));
}
__device__ __forceinline__ f2 lane_swap2(f2 v) {
    f2 r; r.x = lane_swap(v.x); r.y = lane_swap(v.y); return r;
}
__device__ __forceinline__ float tanh_fast(float a) {
    const float e = __expf(2.f * a);
    return 1.f - 2.f * __builtin_amdgcn_rcpf(e + 1.f);
}

// ===========================================================================
// PREP (1 block, 128 threads): the variational circuit is input-independent,
// so collapse it to one 64x64 complex unitary U by simulating the 64 basis
// states (2-lane packed sim, verbatim from the verified R7 kernel), then
// emit MFMA-A-fragment-ordered fp16 weights into d_ws:
//   W1 frags [0,16KB): rows 2n/2n+1 = Re/Im U[n][k]   (128x64, 16 frags)
//   W2 frags [16KB,18KB): SW[k2][j] = sum_q SIGNS[k2][q]*post_w1[q][j] (64x16)
// A-frag layout (16x16x32): lane l, elem e -> A[row=(l&15)+16t][k=(l>>4)*8+e+32*ks]
// ===========================================================================
__global__ __launch_bounds__(128) void prep_kernel(
    const float* __restrict__ qw,
    const float* __restrict__ post_w1,
    __fp16* __restrict__ wfrag)
{
    __shared__ f2    gs2[NGATES * GSTRIDE / 2];
    __shared__ float Ure[64][65];
    __shared__ float Uim[64][65];
    const int tid = threadIdx.x;

    // --- phase A: packed fused gates (RZ*RY*RX), R7 layout ---
    if (tid < NGATES) {
        const int pp = tid * 3;
        float s0 = sinf(qw[pp+0]*0.5f), c0 = cosf(qw[pp+0]*0.5f);
        float s1 = sinf(qw[pp+1]*0.5f), c1 = cosf(qw[pp+1]*0.5f);
        float s2 = sinf(qw[pp+2]*0.5f), c2 = cosf(qw[pp+2]*0.5f);
        const float m00r =  c1*c0, m00i =  s1*s0;
        const float m01r = -s1*c0, m01i = -c1*s0;
        const float m10r =  s1*c0, m10i = -c1*s0;
        const float m11r =  c1*c0, m11i = -s1*s0;
        const float g00r = c2*m00r + s2*m00i, g00i = c2*m00i - s2*m00r;
        const float g01r = c2*m01r + s2*m01i, g01i = c2*m01i - s2*m01r;
        const float g10r = c2*m10r - s2*m10i, g10i = c2*m10i + s2*m10r;
        const float g11r = c2*m11r - s2*m11i, g11i = c2*m11i + s2*m11r;
        float* o = (float*)gs2 + tid * GSTRIDE;
        o[0]=o[1]=g00r;  o[2]=o[3]=g00i;  o[4]=o[5]=-g00i;
        o[6]=o[7]=g01r;  o[8]=o[9]=g01i;  o[10]=o[11]=-g01i;
        o[12]=o[13]=g10r; o[14]=o[15]=g10i; o[16]=o[17]=-g10i;
        o[18]=o[19]=g11r; o[20]=o[21]=g11i; o[22]=o[23]=-g11i;
        o[24]=g00r; o[25]=g10r;  o[26]=g00i; o[27]=g10i;
        o[28]=-g00i; o[29]=-g10i; o[30]=g01r; o[31]=g11r;
        o[32]=g01i; o[33]=g11i;  o[34]=-g01i; o[35]=-g11i;
        o[36]=o[37]=o[38]=o[39]=0.f;
    }
    __syncthreads();

    // --- phase B: simulate basis state (tid>>1) on lane pair; R7 gate loop ---
    {
        const int bt = tid >> 1, p = tid & 1;
        f2 R[16], U[16];
        #pragma unroll
        for (int j = 0; j < 16; ++j) {
            R[j].x = ((bt >> 5) == p && (bt & 31) == 2*j    ) ? 1.f : 0.f;
            R[j].y = ((bt >> 5) == p && (bt & 31) == 2*j + 1) ? 1.f : 0.f;
            U[j].x = 0.f; U[j].y = 0.f;
        }
        const f2* gpack = gs2;
        #pragma unroll 1
        for (int l = 0; l < NLAYERS; ++l) {
            #pragma unroll
            for (int j = 0; j < 16; j += 2) {
                float t;
                t = R[j].y; R[j].y = R[j+1].y; R[j+1].y = t;
                t = U[j].y; U[j].y = U[j+1].y; U[j+1].y = t;
            }
            #pragma unroll
            for (int c = 1; c < 4; ++c) {
                #pragma unroll
                for (int j = 0; j < 16; ++j) {
                    if (((j >> (c-1)) & 1) && !((j >> c) & 1)) {
                        const int t = j | (1 << c);
                        f2 tmp;
                        tmp = R[j]; R[j] = R[t]; R[t] = tmp;
                        tmp = U[j]; U[j] = U[t]; U[t] = tmp;
                    }
                }
            }
            #pragma unroll
            for (int j = 8; j < 16; ++j) {
                R[j] = lane_swap2(R[j]);
                U[j] = lane_swap2(U[j]);
            }
            const f2* lg = gpack + l * (NQ * (GSTRIDE / 2));
            {
                const f2* gb = lg;
                const f2 A = gb[12], Ai = gb[13], nAi = gb[14];
                const f2 C = gb[15], Ci = gb[16], nCi = gb[17];
                #pragma unroll
                for (int j = 0; j < 16; ++j) {
                    const f2 z = R[j], u = U[j];
                    const f2 br0 = __builtin_shufflevector(z, z, 0, 0);
                    const f2 br1 = __builtin_shufflevector(z, z, 1, 1);
                    const f2 bu0 = __builtin_shufflevector(u, u, 0, 0);
                    const f2 bu1 = __builtin_shufflevector(u, u, 1, 1);
                    R[j] = __builtin_elementwise_fma(nCi, bu1, __builtin_elementwise_fma(C,  br1, __builtin_elementwise_fma(nAi, bu0, A  * br0)));
                    U[j] = __builtin_elementwise_fma(C,   bu1, __builtin_elementwise_fma(Ci, br1, __builtin_elementwise_fma(A,   bu0, Ai * br0)));
                }
            }
            #pragma unroll
            for (int q = 1; q < 5; ++q) {
                const f2* gb = lg + q * (GSTRIDE / 2);
                const f2 a00r = gb[0], a00i = gb[1],  n00i = gb[2];
                const f2 a01r = gb[3], a01i = gb[4],  n01i = gb[5];
                const f2 a10r = gb[6], a10i = gb[7],  n10i = gb[8];
                const f2 a11r = gb[9], a11i = gb[10], n11i = gb[11];
                const int bit = 1 << (q - 1);
                #pragma unroll
                for (int m = 0; m < 8; ++m) {
                    const int ja = ((m >> (q-1)) << q) | (m & (bit - 1));
                    const int jb = ja | bit;
                    const f2 zr0 = R[ja], zu0 = U[ja];
                    const f2 zr1 = R[jb], zu1 = U[jb];
                    R[ja] = __builtin_elementwise_fma(n01i, zu1, __builtin_elementwise_fma(a01r, zr1, __builtin_elementwise_fma(n00i, zu0, a00r * zr0)));
                    U[ja] = __builtin_elementwise_fma(a01r, zu1, __builtin_elementwise_fma(a01i, zr1, __builtin_elementwise_fma(a00r, zu0, a00i * zr0)));
                    R[jb] = __builtin_elementwise_fma(n11i, zu1, __builtin_elementwise_fma(a11r, zr1, __builtin_elementwise_fma(n10i, zu0, a10r * zr0)));
                    U[jb] = __builtin_elementwise_fma(a11r, zu1, __builtin_elementwise_fma(a11i, zr1, __builtin_elementwise_fma(a10r, zu0, a10i * zr0)));
                }
            }
            {
                const f2* gb = lg + 5 * (GSTRIDE / 2);
                const bool sw = (p != 0);
                const f2 rrr  = sw ? gb[9]  : gb[0];
                const f2 rri  = sw ? gb[10] : gb[1];
                const f2 nrri = sw ? gb[11] : gb[2];
                const f2 rpr  = sw ? gb[6]  : gb[3];
                const f2 rpi  = sw ? gb[7]  : gb[4];
                const f2 nrpi = sw ? gb[8]  : gb[5];
                #pragma unroll
                for (int j = 0; j < 16; ++j) {
                    const f2 z = R[j], u = U[j];
                    const f2 pr = lane_swap2(z), pu = lane_swap2(u);
                    R[j] = __builtin_elementwise_fma(nrpi, pu, __builtin_elementwise_fma(rpr, pr, __builtin_elementwise_fma(nrri, u, rrr * z)));
                    U[j] = __builtin_elementwise_fma(rpr,  pu, __builtin_elementwise_fma(rpi, pr, __builtin_elementwise_fma(rrr,  u, rri * z)));
                }
            }
        }
        #pragma unroll
        for (int j = 0; j < 16; ++j) {
            Ure[32*p + 2*j    ][bt] = R[j].x;
            Ure[32*p + 2*j + 1][bt] = R[j].y;
            Uim[32*p + 2*j    ][bt] = U[j].x;
            Uim[32*p + 2*j + 1][bt] = U[j].y;
        }
    }
    __syncthreads();

    // --- phase C: fragment build (wave 0 only) ---
    if (tid < 64) {
        const int rlow = tid & 15, kg = tid >> 4;
        for (int f = 0; f < 16; ++f) {
            const int otile = f >> 1, ks = f & 1;
            const int row = 16*otile + rlow;
            const int n = row >> 1, cmp = row & 1;
            h8v v;
            #pragma unroll
            for (int e = 0; e < 8; ++e) {
                const int k = kg*8 + e + 32*ks;
                v[e] = (__fp16)(cmp ? Uim[n][k] : Ure[n][k]);
            }
            *(h8v*)(wfrag + f*512 + tid*8) = v;
        }
        float cw[6];
        #pragma unroll
        for (int q = 0; q < 6; ++q) cw[q] = post_w1[q*16 + rlow];
        for (int f = 0; f < 2; ++f) {
            h8v v;
            #pragma unroll
            for (int e = 0; e < 8; ++e) {
                const int k2 = kg*8 + e + 32*f;
                float s = 0.f;
                #pragma unroll
                for (int q = 0; q < 6; ++q)
                    s += ((k2 >> q) & 1) ? -cw[q] : cw[q];
                v[e] = (__fp16)s;
            }
            *(h8v*)(wfrag + 8192 + f*512 + tid*8) = v;
        }
    }
}

// ===========================================================================
// MAIN: 4 waves/block, each wave owns 64 samples. Per 16-sample group G:
// build enc B-frags in-register (bpermute of per-sample trig factors),
// GEMM1 (16 MFMA) -> psi, p=|psi|^2 in-lane (re/im = adjacent C rows),
// p -> swizzled per-wave LDS tile (byte off 2n ^ (sl&7)<<4; write = exactly
// 2 lanes/bank = free), B2-frags via b128 read, GEMM2 (2 MFMA) -> h2pre,
// relu + 16->4 + shfl reduce over lane groups -> float4 store.
// ===========================================================================
__global__ __launch_bounds__(256) void qnn_mfma_kernel(
    const float* __restrict__ x,
    const float* __restrict__ pre_w1, const float* __restrict__ pre_b1,
    const float* __restrict__ pre_w2, const float* __restrict__ pre_b2,
    const __fp16* __restrict__ wfrag,
    const float* __restrict__ post_b1, const float* __restrict__ post_w2,
    const float* __restrict__ post_b2,
    float* __restrict__ out)
{
    __shared__ __align__(16) __fp16 w1s[8192];      // W1 frags, 16 KB
    __shared__ __align__(16) __fp16 ps[4][1024];    // per-wave p tile, 2 KB ea
    const int tid = threadIdx.x;
    {
        const uint4* src = (const uint4*)wfrag;
        uint4* dst = (uint4*)w1s;
        #pragma unroll
        for (int i = 0; i < 4; ++i) dst[tid + i*256] = src[tid + i*256];
    }
    __syncthreads();

    const int lane = tid & 63, wid = tid >> 6;
    const int sbase = (blockIdx.x * 4 + wid) * 64;

    const h8v a2f0 = *(const h8v*)(wfrag + 8192 + lane*8);
    const h8v a2f1 = *(const h8v*)(wfrag + 8192 + 512 + lane*8);

    // --- scalar phase: thread = sample ---
    const float4 xv = ((const float4*)x)[sbase + lane];
    float h[16];
    #pragma unroll
    for (int j = 0; j < 16; ++j) {
        float a = pre_b1[j];
        a = fmaf(xv.x, pre_w1[0*16+j], a);
        a = fmaf(xv.y, pre_w1[1*16+j], a);
        a = fmaf(xv.z, pre_w1[2*16+j], a);
        a = fmaf(xv.w, pre_w1[3*16+j], a);
        h[j] = fmaxf(a, 0.f);
    }
    // per-qubit factors: f_q(0)=cos(y), f_q(1)=sin(y), y = tanh(z)/2 + pi/4
    float fc[NQ], fs[NQ];
    #pragma unroll
    for (int q = 0; q < NQ; ++q) {
        float a = pre_b2[q];
        #pragma unroll
        for (int j = 0; j < 16; ++j) a = fmaf(h[j], pre_w2[j*NQ+q], a);
        const float y = 0.5f * tanh_fast(a) + 0.78539816339744831f;
        fc[q] = __cosf(y); fs[q] = __sinf(y);
    }
    const float b2x = post_b2[0], b2y = post_b2[1];
    const float b2z = post_b2[2], b2w = post_b2[3];

    const int sl = lane & 15, g = lane >> 4;
    const int swz = (sl & 7) << 4;
    __fp16* myp = ps[wid];

    #pragma unroll
    for (int G = 0; G < 4; ++G) {
        const int srcb = (G * 16 + sl) << 2;
        #define BP(v) __int_as_float(__builtin_amdgcn_ds_bpermute(srcb, __float_as_int(v)))
        const float q0c=BP(fc[0]), q0s=BP(fs[0]);
        const float q1c=BP(fc[1]), q1s=BP(fs[1]);
        const float q2c=BP(fc[2]), q2s=BP(fs[2]);
        const float q3c=BP(fc[3]), q3s=BP(fs[3]);
        const float q4c=BP(fc[4]), q4s=BP(fs[4]);
        const float q5c=BP(fc[5]), q5s=BP(fs[5]);
        #undef BP
        const float f3  = (g & 1) ? q3s : q3c;
        const float f4  = (g & 2) ? q4s : q4c;
        const float f34 = f3 * f4;
        const float pre0 = f34 * q5c, pre1 = f34 * q5s;
        float t01[4], b8[8];
        t01[0] = q0c*q1c; t01[1] = q0s*q1c; t01[2] = q0c*q1s; t01[3] = q0s*q1s;
        #pragma unroll
        for (int e = 0; e < 8; ++e) b8[e] = t01[e & 3] * ((e & 4) ? q2s : q2c);
        h8v bf0, bf1;
        #pragma unroll
        for (int e2 = 0; e2 < 4; ++e2) {
            const h2v t0 = __builtin_amdgcn_cvt_pkrtz(b8[2*e2]*pre0, b8[2*e2+1]*pre0);
            const h2v t1 = __builtin_amdgcn_cvt_pkrtz(b8[2*e2]*pre1, b8[2*e2+1]*pre1);
            bf0[2*e2] = t0[0]; bf0[2*e2+1] = t0[1];
            bf1[2*e2] = t1[0]; bf1[2*e2+1] = t1[1];
        }

        // GEMM1: 128 psi rows (re/im interleaved) x 16 samples, K=64
        f4v acc[8];
        #pragma unroll
        for (int t = 0; t < 8; ++t) {
            const h8v a0 = *(const h8v*)(w1s + (t*2+0)*512 + lane*8);
            const h8v a1 = *(const h8v*)(w1s + (t*2+1)*512 + lane*8);
            f4v z = {0.f, 0.f, 0.f, 0.f};
            z = __builtin_amdgcn_mfma_f32_16x16x32_f16(a0, bf0, z, 0, 0, 0);
            acc[t] = __builtin_amdgcn_mfma_f32_16x16x32_f16(a1, bf1, z, 0, 0, 0);
        }
        // p = re^2+im^2 (adjacent C rows), to swizzled LDS (byte = 2n ^ swz)
        #pragma unroll
        for (int t = 0; t < 8; ++t) {
            const float p0 = fmaf(acc[t].x, acc[t].x, acc[t].y * acc[t].y);
            const float p1 = fmaf(acc[t].z, acc[t].z, acc[t].w * acc[t].w);
            const h2v ph = __builtin_amdgcn_cvt_pkrtz(p0, p1);
            *(h2v*)((char*)myp + sl*128 + ((16*t + 4*g) ^ swz)) = ph;
        }
        // B2 frags + GEMM2 -> 16 h2pre rows x 16 samples, K=64
        const h8v pb0 = *(const h8v*)((const char*)myp + sl*128 + ((16*g     ) ^ swz));
        const h8v pb1 = *(const h8v*)((const char*)myp + sl*128 + ((16*g + 64) ^ swz));
        f4v c2 = {0.f, 0.f, 0.f, 0.f};
        c2 = __builtin_amdgcn_mfma_f32_16x16x32_f16(a2f0, pb0, c2, 0, 0, 0);
        c2 = __builtin_amdgcn_mfma_f32_16x16x32_f16(a2f1, pb1, c2, 0, 0, 0);

        // epilogue: relu(c2 + b1[4g+r]), 16->4, reduce over g, store
        const float4 b1v = ((const float4*)post_b1)[g];
        const float e0  = fmaxf(c2.x + b1v.x, 0.f);
        const float e1  = fmaxf(c2.y + b1v.y, 0.f);
        const float e2_ = fmaxf(c2.z + b1v.z, 0.f);
        const float e3  = fmaxf(c2.w + b1v.w, 0.f);
        const float4 w0 = ((const float4*)post_w2)[4*g + 0];
        const float4 w1 = ((const float4*)post_w2)[4*g + 1];
        const float4 w2 = ((const float4*)post_w2)[4*g + 2];
        const float4 w3 = ((const float4*)post_w2)[4*g + 3];
        float ox = fmaf(e0, w0.x, fmaf(e1, w1.x, fmaf(e2_, w2.x, e3 * w3.x)));
        float oy = fmaf(e0, w0.y, fmaf(e1, w1.y, fmaf(e2_, w2.y, e3 * w3.y)));
        float oz = fmaf(e0, w0.z, fmaf(e1, w1.z, fmaf(e2_, w2.z, e3 * w3.z)));
        float ow = fmaf(e0, w0.w, fmaf(e1, w1.w, fmaf(e2_, w2.w, e3 * w3.w)));
        ox += __shfl_xor(ox, 16, 64); ox += __shfl_xor(ox, 32, 64);
        oy += __shfl_xor(oy, 16, 64); oy += __shfl_xor(oy, 32, 64);
        oz += __shfl_xor(oz, 16, 64); oz += __shfl_xor(oz, 32, 64);
        ow += __shfl_xor(ow, 16, 64); ow += __shfl_xor(ow, 32, 64);
        if (lane < 16) {
            float4 r;
            r.x = ox + b2x; r.y = oy + b2y; r.z = oz + b2z; r.w = ow + b2w;
            ((float4*)out)[sbase + G*16 + sl] = r;
        }
    }
}

extern "C" void kernel_launch(void* const* d_in, const int* in_sizes, int n_in,
                              void* d_out, int out_size, void* d_ws, size_t ws_size,
                              hipStream_t stream) {
    const float* x       = (const float*)d_in[0];
    const float* pre_w1  = (const float*)d_in[1];
    const float* pre_b1  = (const float*)d_in[2];
    const float* pre_w2  = (const float*)d_in[3];
    const float* pre_b2  = (const float*)d_in[4];
    const float* qw      = (const float*)d_in[5];
    const float* post_w1 = (const float*)d_in[6];
    const float* post_b1 = (const float*)d_in[7];
    const float* post_w2 = (const float*)d_in[8];
    const float* post_b2 = (const float*)d_in[9];
    float* out = (float*)d_out;
    __fp16* wfrag = (__fp16*)d_ws;   // 18 KB of fragment weights

    prep_kernel<<<1, 128, 0, stream>>>(qw, post_w1, wfrag);
    qnn_mfma_kernel<<<QBATCH / 256, 256, 0, stream>>>(
        x, pre_w1, pre_b1, pre_w2, pre_b2, wfrag,
        post_b1, post_w2, post_b2, out);
}

// Round 10
// 25.528 us; speedup vs baseline: 11.2896x; 1.0242x over previous
//
#include <hip/hip_runtime.h>
#include <math.h>

#define NQ 6
#define NLAYERS 3
#define QBATCH 262144
#define NGATES 18
#define GSTRIDE 40

typedef float  f2   __attribute__((ext_vector_type(2)));
typedef float  f4v  __attribute__((ext_vector_type(4)));
typedef float  f16f __attribute__((ext_vector_type(16)));
typedef __fp16 h2v  __attribute__((ext_vector_type(2)));
typedef __fp16 h8v  __attribute__((ext_vector_type(8)));

__device__ __forceinline__ float lane_swap(float v) {
    return __int_as_float(__builtin_amdgcn_update_dpp(
        0, __float_as_int(v), 0xB1, 0xF, 0xF, true));
}
__device__ __forceinline__ f2 lane_swap2(f2 v) {
    f2 r; r.x = lane_swap(v.x); r.y = lane_swap(v.y); return r;
}
__device__ __forceinline__ float tanh_fast(float a) {
    const float e = __expf(2.f * a);
    return 1.f - 2.f * __builtin_amdgcn_rcpf(e + 1.f);
}

// ===========================================================================
// PREP (1 block, 128 threads): collapse the input-independent variational
// circuit to one 64x64 complex unitary U (2-lane packed sim, verbatim from
// the verified R7 kernel), then emit MFMA-fragment-ordered fp16 weights:
//   [0,16KB): GEMM1 A-frags, 32x32x16 layout: frag i=(T*4+s), lane l, elem e
//             -> A[row=32T+(l&31)][k=(l>>5)*8+16s+e], row 2n+c = Re/Im U[n][.]
//   [16KB,18KB): GEMM2 A-frags, 16x16x32 layout: SW[k2][j] =
//             sum_q SIGNS[k2][q]*post_w1[q][j]
// ===========================================================================
__global__ __launch_bounds__(128) void prep_kernel(
    const float* __restrict__ qw,
    const float* __restrict__ post_w1,
    __fp16* __restrict__ wfrag)
{
    __shared__ f2    gs2[NGATES * GSTRIDE / 2];
    __shared__ float Ure[64][65];
    __shared__ float Uim[64][65];
    const int tid = threadIdx.x;

    // --- phase A: packed fused gates (RZ*RY*RX), R7 layout ---
    if (tid < NGATES) {
        const int pp = tid * 3;
        float s0 = sinf(qw[pp+0]*0.5f), c0 = cosf(qw[pp+0]*0.5f);
        float s1 = sinf(qw[pp+1]*0.5f), c1 = cosf(qw[pp+1]*0.5f);
        float s2 = sinf(qw[pp+2]*0.5f), c2 = cosf(qw[pp+2]*0.5f);
        const float m00r =  c1*c0, m00i =  s1*s0;
        const float m01r = -s1*c0, m01i = -c1*s0;
        const float m10r =  s1*c0, m10i = -c1*s0;
        const float m11r =  c1*c0, m11i = -s1*s0;
        const float g00r = c2*m00r + s2*m00i, g00i = c2*m00i - s2*m00r;
        const float g01r = c2*m01r + s2*m01i, g01i = c2*m01i - s2*m01r;
        const float g10r = c2*m10r - s2*m10i, g10i = c2*m10i + s2*m10r;
        const float g11r = c2*m11r - s2*m11i, g11i = c2*m11i + s2*m11r;
        float* o = (float*)gs2 + tid * GSTRIDE;
        o[0]=o[1]=g00r;  o[2]=o[3]=g00i;  o[4]=o[5]=-g00i;
        o[6]=o[7]=g01r;  o[8]=o[9]=g01i;  o[10]=o[11]=-g01i;
        o[12]=o[13]=g10r; o[14]=o[15]=g10i; o[16]=o[17]=-g10i;
        o[18]=o[19]=g11r; o[20]=o[21]=g11i; o[22]=o[23]=-g11i;
        o[24]=g00r; o[25]=g10r;  o[26]=g00i; o[27]=g10i;
        o[28]=-g00i; o[29]=-g10i; o[30]=g01r; o[31]=g11r;
        o[32]=g01i; o[33]=g11i;  o[34]=-g01i; o[35]=-g11i;
        o[36]=o[37]=o[38]=o[39]=0.f;
    }
    __syncthreads();

    // --- phase B: simulate basis state (tid>>1) on lane pair; R7 gate loop ---
    {
        const int bt = tid >> 1, p = tid & 1;
        f2 R[16], U[16];
        #pragma unroll
        for (int j = 0; j < 16; ++j) {
            R[j].x = ((bt >> 5) == p && (bt & 31) == 2*j    ) ? 1.f : 0.f;
            R[j].y = ((bt >> 5) == p && (bt & 31) == 2*j + 1) ? 1.f : 0.f;
            U[j].x = 0.f; U[j].y = 0.f;
        }
        const f2* gpack = gs2;
        #pragma unroll 1
        for (int l = 0; l < NLAYERS; ++l) {
            #pragma unroll
            for (int j = 0; j < 16; j += 2) {
                float t;
                t = R[j].y; R[j].y = R[j+1].y; R[j+1].y = t;
                t = U[j].y; U[j].y = U[j+1].y; U[j+1].y = t;
            }
            #pragma unroll
            for (int c = 1; c < 4; ++c) {
                #pragma unroll
                for (int j = 0; j < 16; ++j) {
                    if (((j >> (c-1)) & 1) && !((j >> c) & 1)) {
                        const int t = j | (1 << c);
                        f2 tmp;
                        tmp = R[j]; R[j] = R[t]; R[t] = tmp;
                        tmp = U[j]; U[j] = U[t]; U[t] = tmp;
                    }
                }
            }
            #pragma unroll
            for (int j = 8; j < 16; ++j) {
                R[j] = lane_swap2(R[j]);
                U[j] = lane_swap2(U[j]);
            }
            const f2* lg = gpack + l * (NQ * (GSTRIDE / 2));
            {
                const f2* gb = lg;
                const f2 A = gb[12], Ai = gb[13], nAi = gb[14];
                const f2 C = gb[15], Ci = gb[16], nCi = gb[17];
                #pragma unroll
                for (int j = 0; j < 16; ++j) {
                    const f2 z = R[j], u = U[j];
                    const f2 br0 = __builtin_shufflevector(z, z, 0, 0);
                    const f2 br1 = __builtin_shufflevector(z, z, 1, 1);
                    const f2 bu0 = __builtin_shufflevector(u, u, 0, 0);
                    const f2 bu1 = __builtin_shufflevector(u, u, 1, 1);
                    R[j] = __builtin_elementwise_fma(nCi, bu1, __builtin_elementwise_fma(C,  br1, __builtin_elementwise_fma(nAi, bu0, A  * br0)));
                    U[j] = __builtin_elementwise_fma(C,   bu1, __builtin_elementwise_fma(Ci, br1, __builtin_elementwise_fma(A,   bu0, Ai * br0)));
                }
            }
            #pragma unroll
            for (int q = 1; q < 5; ++q) {
                const f2* gb = lg + q * (GSTRIDE / 2);
                const f2 a00r = gb[0], a00i = gb[1],  n00i = gb[2];
                const f2 a01r = gb[3], a01i = gb[4],  n01i = gb[5];
                const f2 a10r = gb[6], a10i = gb[7],  n10i = gb[8];
                const f2 a11r = gb[9], a11i = gb[10], n11i = gb[11];
                const int bit = 1 << (q - 1);
                #pragma unroll
                for (int m = 0; m < 8; ++m) {
                    const int ja = ((m >> (q-1)) << q) | (m & (bit - 1));
                    const int jb = ja | bit;
                    const f2 zr0 = R[ja], zu0 = U[ja];
                    const f2 zr1 = R[jb], zu1 = U[jb];
                    R[ja] = __builtin_elementwise_fma(n01i, zu1, __builtin_elementwise_fma(a01r, zr1, __builtin_elementwise_fma(n00i, zu0, a00r * zr0)));
                    U[ja] = __builtin_elementwise_fma(a01r, zu1, __builtin_elementwise_fma(a01i, zr1, __builtin_elementwise_fma(a00r, zu0, a00i * zr0)));
                    R[jb] = __builtin_elementwise_fma(n11i, zu1, __builtin_elementwise_fma(a11r, zr1, __builtin_elementwise_fma(n10i, zu0, a10r * zr0)));
                    U[jb] = __builtin_elementwise_fma(a11r, zu1, __builtin_elementwise_fma(a11i, zr1, __builtin_elementwise_fma(a10r, zu0, a10i * zr0)));
                }
            }
            {
                const f2* gb = lg + 5 * (GSTRIDE / 2);
                const bool sw = (p != 0);
                const f2 rrr  = sw ? gb[9]  : gb[0];
                const f2 rri  = sw ? gb[10] : gb[1];
                const f2 nrri = sw ? gb[11] : gb[2];
                const f2 rpr  = sw ? gb[6]  : gb[3];
                const f2 rpi  = sw ? gb[7]  : gb[4];
                const f2 nrpi = sw ? gb[8]  : gb[5];
                #pragma unroll
                for (int j = 0; j < 16; ++j) {
                    const f2 z = R[j], u = U[j];
                    const f2 pr = lane_swap2(z), pu = lane_swap2(u);
                    R[j] = __builtin_elementwise_fma(nrpi, pu, __builtin_elementwise_fma(rpr, pr, __builtin_elementwise_fma(nrri, u, rrr * z)));
                    U[j] = __builtin_elementwise_fma(rpr,  pu, __builtin_elementwise_fma(rpi, pr, __builtin_elementwise_fma(rrr,  u, rri * z)));
                }
            }
        }
        #pragma unroll
        for (int j = 0; j < 16; ++j) {
            Ure[32*p + 2*j    ][bt] = R[j].x;
            Ure[32*p + 2*j + 1][bt] = R[j].y;
            Uim[32*p + 2*j    ][bt] = U[j].x;
            Uim[32*p + 2*j + 1][bt] = U[j].y;
        }
    }
    __syncthreads();

    // --- phase C: fragment build, split across both waves ---
    {
        const int lane = tid & 63, w = tid >> 6;
        const int r32 = lane & 31, kh = lane >> 5;
        for (int i = w; i < 16; i += 2) {
            const int T = i >> 2, s = i & 3;
            const int row = 32*T + r32, n = row >> 1, cmp = row & 1;
            const float* src = cmp ? &Uim[n][0] : &Ure[n][0];
            h8v v;
            #pragma unroll
            for (int e = 0; e < 8; ++e) v[e] = (__fp16)src[kh*8 + 16*s + e];
            *(h8v*)(wfrag + i*512 + lane*8) = v;
        }
        if (w == 0) {
            const int rlow = lane & 15, kg = lane >> 4;
            float cw[6];
            #pragma unroll
            for (int q = 0; q < 6; ++q) cw[q] = post_w1[q*16 + rlow];
            for (int f = 0; f < 2; ++f) {
                h8v v;
                #pragma unroll
                for (int e = 0; e < 8; ++e) {
                    const int k2 = kg*8 + e + 32*f;
                    float sacc = 0.f;
                    #pragma unroll
                    for (int q = 0; q < 6; ++q)
                        sacc += ((k2 >> q) & 1) ? -cw[q] : cw[q];
                    v[e] = (__fp16)sacc;
                }
                *(h8v*)(wfrag + 8192 + f*512 + lane*8) = v;
            }
        }
    }
}

// ===========================================================================
// MAIN: 4 waves/block, each wave owns 64 samples in TWO groups of 32.
// GEMM1 = 32x32x16 MFMA (4 row-tiles x 4 K-steps = 16 MFMA / 32 samples).
// A-frags (16 x h8v = 128B/lane) hoisted to registers from global (L2-hit).
// p = |psi|^2 in-lane (re/im = even/odd reg pairs of the 32x32 C layout),
// -> swizzled per-wave LDS tile (32 samples x 64 k2 fp16, XOR byte bits 4-6)
// -> GEMM2 (2x 16x16x32 per 16-sample half) -> relu/16->4/shfl-reduce.
// ===========================================================================
__global__ __launch_bounds__(256) void qnn_mfma_kernel(
    const float* __restrict__ x,
    const float* __restrict__ pre_w1, const float* __restrict__ pre_b1,
    const float* __restrict__ pre_w2, const float* __restrict__ pre_b2,
    const __fp16* __restrict__ wfrag,
    const float* __restrict__ post_b1, const float* __restrict__ post_w2,
    const float* __restrict__ post_b2,
    float* __restrict__ out)
{
    __shared__ __align__(16) __fp16 ps[4][2048];   // per-wave 32x64 p tile, 4KB
    const int tid  = threadIdx.x;
    const int lane = tid & 63, wid = tid >> 6;
    const int sbase = (blockIdx.x * 4 + wid) * 64;

    // hoist GEMM1 A-frags (coalesced, L2-resident after first blocks)
    h8v a1f[16];
    #pragma unroll
    for (int i = 0; i < 16; ++i)
        a1f[i] = *(const h8v*)(wfrag + i*512 + lane*8);
    const h8v a2f0 = *(const h8v*)(wfrag + 8192 + lane*8);
    const h8v a2f1 = *(const h8v*)(wfrag + 8192 + 512 + lane*8);

    // --- scalar phase: thread = sample ---
    const float4 xv = ((const float4*)x)[sbase + lane];
    float h[16];
    #pragma unroll
    for (int j = 0; j < 16; ++j) {
        float a = pre_b1[j];
        a = fmaf(xv.x, pre_w1[0*16+j], a);
        a = fmaf(xv.y, pre_w1[1*16+j], a);
        a = fmaf(xv.z, pre_w1[2*16+j], a);
        a = fmaf(xv.w, pre_w1[3*16+j], a);
        h[j] = fmaxf(a, 0.f);
    }
    float fc[NQ], fs[NQ];
    #pragma unroll
    for (int q = 0; q < NQ; ++q) {
        float a = pre_b2[q];
        #pragma unroll
        for (int j = 0; j < 16; ++j) a = fmaf(h[j], pre_w2[j*NQ+q], a);
        const float y = 0.5f * tanh_fast(a) + 0.78539816339744831f;
        fc[q] = __cosf(y); fs[q] = __sinf(y);
    }
    const float b2x = post_b2[0], b2y = post_b2[1];
    const float b2z = post_b2[2], b2w = post_b2[3];

    const int sl32 = lane & 31, kh = lane >> 5;    // GEMM1 roles
    const int sl16 = lane & 15, g2 = lane >> 4;    // GEMM2 roles
    __fp16* myp = ps[wid];
    const int wswz = (sl32 & 7) << 4;

    #pragma unroll
    for (int G2 = 0; G2 < 2; ++G2) {
        // factors of this lane's GEMM1 sample (G2*32 + sl32)
        const int srcb = (G2 * 32 + sl32) << 2;
        #define BP(v) __int_as_float(__builtin_amdgcn_ds_bpermute(srcb, __float_as_int(v)))
        const float q0c=BP(fc[0]), q0s=BP(fs[0]);
        const float q1c=BP(fc[1]), q1s=BP(fs[1]);
        const float q2c=BP(fc[2]), q2s=BP(fs[2]);
        const float q3c=BP(fc[3]), q3s=BP(fs[3]);
        const float q4c=BP(fc[4]), q4s=BP(fs[4]);
        const float q5c=BP(fc[5]), q5s=BP(fs[5]);
        #undef BP
        // v[k], k = 16s + 8kh + e:  b8[e] (qubits 0-2) * f3(kh) * f4(s&1) * f5(s>>1)
        const float f3v = kh ? q3s : q3c;
        float t01[4], b8[8];
        t01[0] = q0c*q1c; t01[1] = q0s*q1c; t01[2] = q0c*q1s; t01[3] = q0s*q1s;
        #pragma unroll
        for (int e = 0; e < 8; ++e) b8[e] = t01[e & 3] * ((e & 4) ? q2s : q2c);
        h8v bs[4];
        #pragma unroll
        for (int s = 0; s < 4; ++s) {
            const float pre = f3v * ((s & 1) ? q4s : q4c) * ((s & 2) ? q5s : q5c);
            #pragma unroll
            for (int e2 = 0; e2 < 4; ++e2) {
                const h2v t = __builtin_amdgcn_cvt_pkrtz(b8[2*e2]*pre, b8[2*e2+1]*pre);
                bs[s][2*e2] = t[0]; bs[s][2*e2+1] = t[1];
            }
        }

        // GEMM1: 128 psi rows x 32 samples, K=64 (4 tiles x 4 K-steps)
        f16f acc[4];
        #pragma unroll
        for (int T = 0; T < 4; ++T) acc[T] = (f16f)(0.f);
        #pragma unroll
        for (int s = 0; s < 4; ++s) {
            #pragma unroll
            for (int T = 0; T < 4; ++T)
                acc[T] = __builtin_amdgcn_mfma_f32_32x32x16_f16(
                    a1f[T*4 + s], bs[s], acc[T], 0, 0, 0);
        }

        // p = re^2+im^2: reg pairs (4a,4a+1),(4a+2,4a+3) -> k2 = 16T+4a+2kh+{0,1}
        #pragma unroll
        for (int T = 0; T < 4; ++T) {
            #pragma unroll
            for (int a = 0; a < 4; ++a) {
                const float p0 = fmaf(acc[T][4*a+0], acc[T][4*a+0],
                                      acc[T][4*a+1] * acc[T][4*a+1]);
                const float p1 = fmaf(acc[T][4*a+2], acc[T][4*a+2],
                                      acc[T][4*a+3] * acc[T][4*a+3]);
                const h2v ph = __builtin_amdgcn_cvt_pkrtz(p0, p1);
                const int boff = (32*T + 8*a + 4*kh) ^ wswz;
                *(h2v*)((char*)myp + sl32*128 + boff) = ph;
            }
        }

        // GEMM2 per 16-sample half + epilogue
        #pragma unroll
        for (int H = 0; H < 2; ++H) {
            const int smp  = H*16 + sl16;           // sample within 32-tile
            const int rswz = (smp & 7) << 4;
            const h8v pb0 = *(const h8v*)((const char*)myp + smp*128 + ((16*g2     ) ^ rswz));
            const h8v pb1 = *(const h8v*)((const char*)myp + smp*128 + ((16*g2 + 64) ^ rswz));
            f4v c2 = {0.f, 0.f, 0.f, 0.f};
            c2 = __builtin_amdgcn_mfma_f32_16x16x32_f16(a2f0, pb0, c2, 0, 0, 0);
            c2 = __builtin_amdgcn_mfma_f32_16x16x32_f16(a2f1, pb1, c2, 0, 0, 0);

            const float4 b1v = ((const float4*)post_b1)[g2];
            const float e0  = fmaxf(c2.x + b1v.x, 0.f);
            const float e1  = fmaxf(c2.y + b1v.y, 0.f);
            const float e2_ = fmaxf(c2.z + b1v.z, 0.f);
            const float e3  = fmaxf(c2.w + b1v.w, 0.f);
            const float4 w0 = ((const float4*)post_w2)[4*g2 + 0];
            const float4 w1 = ((const float4*)post_w2)[4*g2 + 1];
            const float4 w2 = ((const float4*)post_w2)[4*g2 + 2];
            const float4 w3 = ((const float4*)post_w2)[4*g2 + 3];
            float ox = fmaf(e0, w0.x, fmaf(e1, w1.x, fmaf(e2_, w2.x, e3 * w3.x)));
            float oy = fmaf(e0, w0.y, fmaf(e1, w1.y, fmaf(e2_, w2.y, e3 * w3.y)));
            float oz = fmaf(e0, w0.z, fmaf(e1, w1.z, fmaf(e2_, w2.z, e3 * w3.z)));
            float ow = fmaf(e0, w0.w, fmaf(e1, w1.w, fmaf(e2_, w2.w, e3 * w3.w)));
            ox += __shfl_xor(ox, 16, 64); ox += __shfl_xor(ox, 32, 64);
            oy += __shfl_xor(oy, 16, 64); oy += __shfl_xor(oy, 32, 64);
            oz += __shfl_xor(oz, 16, 64); oz += __shfl_xor(oz, 32, 64);
            ow += __shfl_xor(ow, 16, 64); ow += __shfl_xor(ow, 32, 64);
            if (lane < 16) {
                float4 r;
                r.x = ox + b2x; r.y = oy + b2y; r.z = oz + b2z; r.w = ow + b2w;
                ((float4*)out)[sbase + G2*32 + H*16 + sl16] = r;
            }
        }
    }
}

extern "C" void kernel_launch(void* const* d_in, const int* in_sizes, int n_in,
                              void* d_out, int out_size, void* d_ws, size_t ws_size,
                              hipStream_t stream) {
    const float* x       = (const float*)d_in[0];
    const float* pre_w1  = (const float*)d_in[1];
    const float* pre_b1  = (const float*)d_in[2];
    const float* pre_w2  = (const float*)d_in[3];
    const float* pre_b2  = (const float*)d_in[4];
    const float* qw      = (const float*)d_in[5];
    const float* post_w1 = (const float*)d_in[6];
    const float* post_b1 = (const float*)d_in[7];
    const float* post_w2 = (const float*)d_in[8];
    const float* post_b2 = (const float*)d_in[9];
    float* out = (float*)d_out;
    __fp16* wfrag = (__fp16*)d_ws;   // 18 KB of fragment weights

    prep_kernel<<<1, 128, 0, stream>>>(qw, post_w1, wfrag);
    qnn_mfma_kernel<<<QBATCH / 256, 256, 0, stream>>>(
        x, pre_w1, pre_b1, pre_w2, pre_b2, wfrag,
        post_b1, post_w2, post_b2, out);
}